// Round 17
// baseline (253.045 us; speedup 1.0000x reference)
//
#include <hip/hip_runtime.h>
#include <hip/hip_bf16.h>

using bf16 = __hip_bfloat16;
typedef __attribute__((ext_vector_type(8))) short short8;
typedef __attribute__((ext_vector_type(4))) short short4v;
typedef __attribute__((ext_vector_type(4))) float floatx4;
typedef __attribute__((ext_vector_type(2))) float floatx2;

#define B_    16
#define TASK_ 80
#define LQ_   1024
#define D_    768
#define HH_   12
#define HD_   64
#define LIN_  4096
#define MQ_   (B_*LQ_)     // 16384 query rows
#define MF_   (B_*LIN_)    // 65536 feat rows
#define QR_   (TASK_+LQ_)  // 1104

// ---- workspace layout (bytes) ----
static constexpr size_t OFF_VAL  = 0;                               // fp8 value (B,HH,LIN,HD)
static constexpr size_t OFF_FN   = OFF_VAL + (size_t)MF_*D_*2;      // fp8 fn (MF,768); reused as bf16 sampout
static constexpr size_t OFF_QN   = OFF_FN  + (size_t)MF_*D_*2;      // bf16 qn (MQ,768)
static constexpr size_t OFF_PREP = OFF_QN  + (size_t)MQ_*D_*2;      // compressed prep: 196608 groups x 64B
static constexpr size_t OFF_WVT  = OFF_PREP + (size_t)MQ_*HH_*64;   // fp8 W_val^T (768,768)
static constexpr size_t OFF_WOT  = OFF_WVT + (size_t)D_*D_*2;       // bf16 W_out^T (768,768)
static constexpr size_t OFF_WCT  = OFF_WOT + (size_t)D_*D_*2;       // bf16 Wcat^T (256,768)

__device__ __forceinline__ void async16(const void* g, void* l) {
  __builtin_amdgcn_global_load_lds((const __attribute__((address_space(1))) void*)g,
                                   (__attribute__((address_space(3))) void*)l, 16, 0, 0);
}
__device__ __forceinline__ void async4(const void* g, void* l) {
  __builtin_amdgcn_global_load_lds((const __attribute__((address_space(1))) void*)g,
                                   (__attribute__((address_space(3))) void*)l, 4, 0, 0);
}
__device__ __forceinline__ unsigned char to_fp8(float v) {
  return (unsigned char)(__builtin_amdgcn_cvt_pk_fp8_f32(v, v, 0, false) & 0xff);
}

// merged weight-prep + LayerNorm.
// blocks 0..1055: weight prep. blocks 1056..3103: grid-stride LN, 8192 waves,
// 2-deep row pipeline; fn written fp8 via nontemporal stores (keep L3 for reads).
__global__ __launch_bounds__(256) void k_wln(const float* __restrict__ Wv, const float* __restrict__ Wo,
                                             const float* __restrict__ Woff, const float* __restrict__ Wat,
                                             unsigned char* __restrict__ WvT8, bf16* __restrict__ WoT,
                                             bf16* __restrict__ WcT,
                                             const float* __restrict__ query, const float* __restrict__ feat,
                                             const float* __restrict__ qw, const float* __restrict__ qb,
                                             const float* __restrict__ fw, const float* __restrict__ fb,
                                             bf16* __restrict__ qn, unsigned char* __restrict__ fn8) {
  __shared__ float t[64][65];
  int bid = blockIdx.x;
  if (bid < 288) {
    const float* W = (bid < 144) ? Wv : Wo;
    int lb = (bid < 144) ? bid : bid - 144;
    int bx = lb % 12, by = lb / 12;
    int n0 = bx*64, k0 = by*64;
    int col = threadIdx.x & 63, rg = threadIdx.x >> 6;
    #pragma unroll
    for (int i=0;i<16;++i) { int row = i*4+rg; t[row][col] = W[(size_t)(k0+row)*D_ + n0+col]; }
    __syncthreads();
    if (bid < 144) {
      #pragma unroll
      for (int i=0;i<16;++i) { int row = i*4+rg; WvT8[(size_t)(n0+row)*D_ + k0+col] = to_fp8(t[col][row]); }
    } else {
      #pragma unroll
      for (int i=0;i<16;++i) { int row = i*4+rg; WoT[(size_t)(n0+row)*D_ + k0+col] = __float2bfloat16(t[col][row]); }
    }
    return;
  }
  if (bid < 1056) {
    int idx = (bid-288)*256 + threadIdx.x;     // over 256*768, exact
    int j = idx / D_, k = idx - j*D_;
    float v = 0.f;
    if (j < 96)       v = Woff[(size_t)k*96 + j];
    else if (j < 144) v = Wat[(size_t)k*48 + (j-96)];
    WcT[idx] = __float2bfloat16(v);
    return;
  }
  // ---- LN path: 2-deep pipelined grid-stride ----
  const int gw = (bid-1056)*4 + (threadIdx.x>>6);   // wave id, 0..8191
  const int lane = threadIdx.x & 63;
  const int NW = 2048*4;
  auto rowptr = [&](int r) -> const float* {
    if (r < MQ_) { int bat = r >> 10, rr = r & 1023;
                   return query + ((size_t)bat*QR_ + TASK_ + rr)*D_; }
    return feat + (size_t)(r - MQ_)*D_;
  };
  float4 v[3];
  {
    const float* s0 = rowptr(gw);
    #pragma unroll
    for (int j=0;j<3;++j) v[j] = ((const float4*)s0)[lane + 64*j];
  }
  for (int r = gw; r < MQ_+MF_; r += NW) {
    const int rn = r + NW;
    float4 vn[3];
    if (rn < MQ_+MF_) {
      const float* sn = rowptr(rn);
      #pragma unroll
      for (int j=0;j<3;++j) vn[j] = ((const float4*)sn)[lane + 64*j];
    }
    const bool isQ = (r < MQ_);
    const float* w   = isQ ? qw : fw;
    const float* bia = isQ ? qb : fb;
    float s = 0.f, s2 = 0.f;
    #pragma unroll
    for (int j=0;j<3;++j) {
      s  += v[j].x + v[j].y + v[j].z + v[j].w;
      s2 += v[j].x*v[j].x + v[j].y*v[j].y + v[j].z*v[j].z + v[j].w*v[j].w;
    }
    #pragma unroll
    for (int o=32;o>0;o>>=1){ s += __shfl_xor(s,o); s2 += __shfl_xor(s2,o); }
    float mu  = s*(1.f/D_);
    float var = s2*(1.f/D_) - mu*mu;
    float rstd = rsqrtf(var + 1e-6f);
    #pragma unroll
    for (int j=0;j<3;++j) {
      float4 ww = ((const float4*)w)[lane + 64*j];
      float4 bb = ((const float4*)bia)[lane + 64*j];
      float r0 = (v[j].x-mu)*rstd*ww.x + bb.x;
      float r1 = (v[j].y-mu)*rstd*ww.y + bb.y;
      float r2 = (v[j].z-mu)*rstd*ww.z + bb.z;
      float r3 = (v[j].w-mu)*rstd*ww.w + bb.w;
      if (isQ) {
        short4v o4;
        o4[0] = (short)__bfloat16_as_ushort(__float2bfloat16(r0));
        o4[1] = (short)__bfloat16_as_ushort(__float2bfloat16(r1));
        o4[2] = (short)__bfloat16_as_ushort(__float2bfloat16(r2));
        o4[3] = (short)__bfloat16_as_ushort(__float2bfloat16(r3));
        *(short4v*)(qn + (size_t)r*D_ + 4*(lane + 64*j)) = o4;
      } else {
        unsigned lo = (unsigned)__builtin_amdgcn_cvt_pk_fp8_f32(r0, r1, 0, false);
        unsigned pk = (unsigned)__builtin_amdgcn_cvt_pk_fp8_f32(r2, r3, (int)lo, true);
        __builtin_nontemporal_store(pk, (unsigned*)(fn8 + (size_t)(r-MQ_)*D_ + 4*(lane + 64*j)));
      }
    }
    #pragma unroll
    for (int j=0;j<3;++j) v[j] = vn[j];
  }
}

// fused off/attw GEMM + prep + copytt (r11-verified).
__global__ __launch_bounds__(256) void k_offprep(const bf16* __restrict__ A, const bf16* __restrict__ BT,
                                                 const float* __restrict__ b_off, const float* __restrict__ b_attw,
                                                 const float* __restrict__ refp, char* __restrict__ prepc,
                                                 const float* __restrict__ query, float* __restrict__ out) {
  __shared__ char lds[49152];
  const int tid = threadIdx.x, wid = tid>>6, lane = tid&63;
  const int bm = blockIdx.x*64;
  const int K = D_;
  const int srow = tid>>2;
  const int skb = ((tid&3) ^ ((tid>>3)&3))*8;
  const bf16* gA  = A  + (size_t)(bm + srow)*K + skb;
  const bf16* gB  = BT + (size_t)srow*K + skb;
  const int dstbase = wid<<10;
  const int rb = (lane&15)*64 + ((((lane>>4) ^ ((lane>>1)&3)))<<4);
  floatx4 acc[4][3] = {};
  auto stage = [&](int k0, char* buf) {
    async16(gA + k0,                 buf + dstbase);
    async16(gB + k0,                 buf + 4096  + dstbase);
    async16(gB + (size_t)64*K + k0,  buf + 8192  + dstbase);
    async16(gB + (size_t)128*K + k0, buf + 12288 + dstbase);
  };
  stage(0,  lds);
  stage(32, lds + 16384);
  const int NT = K >> 5;
  int cur = 0, nxt = 2;
  for (int k = 0; k < NT; ++k) {
    if (k < NT-1) asm volatile("s_waitcnt vmcnt(4)" ::: "memory");
    else          asm volatile("s_waitcnt vmcnt(0)" ::: "memory");
    __builtin_amdgcn_s_barrier();
    __builtin_amdgcn_sched_barrier(0);
    if (k + 2 < NT) stage((k+2)*32, lds + nxt*16384);
    const char* ldsA = lds + cur*16384; const char* ldsB = ldsA + 4096;
    short8 af[4], bf[3];
    #pragma unroll
    for (int i=0;i<4;++i) af[i] = *(const short8*)(ldsA + (i*16)*64 + rb);
    #pragma unroll
    for (int j=0;j<3;++j) bf[j] = *(const short8*)(ldsB + (wid*48 + j*16)*64 + rb);
    #pragma unroll
    for (int mi=0;mi<4;++mi)
      #pragma unroll
      for (int ni=0;ni<3;++ni)
        acc[mi][ni] = __builtin_amdgcn_mfma_f32_16x16x32_bf16(af[mi], bf[ni], acc[mi][ni], 0, 0, 0);
    cur = (cur==2) ? 0 : cur+1;
    nxt = (nxt==2) ? 0 : nxt+1;
  }
  __syncthreads();
  float* oa = (float*)lds;         // [64][148]
  const int rowb = (lane>>4)*4, col = lane&15;
  #pragma unroll
  for (int mi=0;mi<4;++mi) {
    #pragma unroll
    for (int ni=0;ni<3;++ni) {
      const int gn = wid*48 + ni*16 + col;
      if (gn < 144) {
        const float bv = (gn < 96) ? b_off[gn] : b_attw[gn-96];
        #pragma unroll
        for (int r=0;r<4;++r) {
          const int rl = mi*16 + rowb + r;
          oa[rl*148 + gn] = acc[mi][ni][r] + bv;
        }
      }
    }
  }
  __syncthreads();
  #pragma unroll
  for (int i=0;i<12;++i) {
    int item = tid + i*256;
    int rl = item / 48;
    int hp = item - rl*48;
    int h = hp >> 2, p = hp & 3;
    int m = bm + rl;
    const float* row = oa + rl*148;
    float l0 = row[96+h*4+0], l1 = row[96+h*4+1], l2 = row[96+h*4+2], l3 = row[96+h*4+3];
    float mx = fmaxf(fmaxf(l0,l1), fmaxf(l2,l3));
    float e0 = expf(l0-mx), e1 = expf(l1-mx), e2 = expf(l2-mx), e3 = expf(l3-mx);
    float inv = 1.f/(e0+e1+e2+e3);
    float ep = (p==0)?e0:(p==1)?e1:(p==2)?e2:e3;
    float awp = ep*inv;
    float x = refp[(size_t)m*2+0]*64.f - 0.5f + row[h*8+p*2+0];
    float y = refp[(size_t)m*2+1]*64.f - 0.5f + row[h*8+p*2+1];
    float x0f = floorf(x), y0f = floorf(y);
    int ix = (int)x0f, iy = (int)y0f;
    float fx = x-x0f, fy = y-y0f;
    float wx[2] = {1.f-fx, fx}, wy[2] = {1.f-fy, fy};
    short4v wq, pq;
    #pragma unroll
    for (int c=0;c<4;++c) {
      int dx = c&1, dy = c>>1;
      int xc = ix+dx, yc = iy+dy;
      bool valid = ((unsigned)xc < 64u) && ((unsigned)yc < 64u);
      float w = valid ? awp*wx[dx]*wy[dy] : 0.f;
      int xi = min(max(xc,0),63), yi = min(max(yc,0),63);
      wq[c] = (short)__bfloat16_as_ushort(__float2bfloat16(w));
      pq[c] = (short)(yi*64+xi);
    }
    char* gb = prepc + ((size_t)(m*HH_ + h))*64;
    *(short4v*)(gb + p*8)      = wq;
    *(short4v*)(gb + 32 + p*8) = pq;
  }
  #pragma unroll
  for (int i=0;i<4;++i) {
    int ci = blockIdx.x*256 + tid + i*65536;
    if (ci < B_*TASK_*D_/4) {
      const int perb = TASK_*D_/4;
      int b = ci / perb, r = ci - b*perb;
      const float4* s = (const float4*)(query + (size_t)b*QR_*D_) + r;
      float4* dd = (float4*)(out + (size_t)b*QR_*D_) + r;
      *dd = *s;
    }
  }
}

// fp8 x fp8 value GEMM (r16-verified): 256x256, 4-phase double-barrier
// lockstep, ring-3, counted vmcnt(8), width-4 swizzled staging.
__global__ __launch_bounds__(512, 2) void k_gemm_fp8(const unsigned char* __restrict__ A,
                                                     const unsigned char* __restrict__ BT,
                                                     const float* __restrict__ bias0,
                                                     unsigned char* __restrict__ outp) {
  __shared__ char lds[49152];    // 3 x (A 8KB + B 8KB)
  const int tid = threadIdx.x, wid = tid>>6, lane = tid&63;
  const int nwg = gridDim.x*gridDim.y;            // 768; %8==0
  const int d = blockIdx.y*gridDim.x + blockIdx.x;
  const int logical = (d & 7)*(nwg>>3) + (d>>3);  // XCD-chunked
  const int bm = (logical/3)*256, bn = (logical%3)*256;
  const int wm = wid>>2, wn = wid&3;              // wave tile 128x64
  int srcAoff[4], srcBoff[4];
  #pragma unroll
  for (int i=0;i<4;++i) {
    int g = wid*64 + lane + i*512;
    int row = g >> 3, sp = (g>>1)&3, half = g&1;
    int s = sp ^ ((row>>2)&3);
    srcAoff[i] = (bm + row)*D_ + s*8 + half*4;
    srcBoff[i] = (bn + row)*D_ + s*8 + half*4;
  }
  const int dstb = wid*256;
  const int rx = (lane&15)*32 + ((((lane>>4) ^ ((lane>>2)&3)))<<3);
  floatx4 acc[8][4] = {};
  auto stageAll = [&](int k0, char* buf) {
    #pragma unroll
    for (int i=0;i<4;++i) async4(A + srcAoff[i] + k0, buf + i*2048 + dstb);
    #pragma unroll
    for (int i=0;i<4;++i) async4(BT + srcBoff[i] + k0, buf + 8192 + i*2048 + dstb);
  };
  stageAll(0,  lds);
  stageAll(32, lds + 16384);
  const int NT = D_ >> 5;     // 24
  int cur = 0, nxt = 2;
  for (int k = 0; k < NT; ++k) {
    if (k < NT-1) asm volatile("s_waitcnt vmcnt(8)" ::: "memory");
    else          asm volatile("s_waitcnt vmcnt(0)" ::: "memory");
    __builtin_amdgcn_s_barrier();
    __builtin_amdgcn_sched_barrier(0);
    const int kk = (k+2)*32;
    const bool pf = (k+2 < NT);
    const char* lA = lds + cur*16384;
    const char* lB = lA + 8192;
    char* bufn = lds + nxt*16384;
    long af[8], bfr[4];
    if (pf) { async4(A+srcAoff[0]+kk, bufn + dstb); async4(A+srcAoff[1]+kk, bufn + 2048 + dstb); }
    #pragma unroll
    for (int i=0;i<4;++i) af[i] = *(const long*)(lA + (wm*128 + i*16)*32 + rx);
    #pragma unroll
    for (int i=0;i<2;++i) bfr[i] = *(const long*)(lB + (wn*64 + i*16)*32 + rx);
    __builtin_amdgcn_s_barrier();
    __builtin_amdgcn_s_setprio(1);
    #pragma unroll
    for (int mi=0;mi<4;++mi)
      #pragma unroll
      for (int ni=0;ni<2;++ni)
        acc[mi][ni] = __builtin_amdgcn_mfma_f32_16x16x32_fp8_fp8(af[mi], bfr[ni], acc[mi][ni], 0, 0, 0);
    __builtin_amdgcn_s_setprio(0);
    __builtin_amdgcn_s_barrier();
    __builtin_amdgcn_sched_barrier(0);
    if (pf) { async4(A+srcAoff[2]+kk, bufn + 4096 + dstb); async4(A+srcAoff[3]+kk, bufn + 6144 + dstb); }
    #pragma unroll
    for (int i=2;i<4;++i) bfr[i] = *(const long*)(lB + (wn*64 + i*16)*32 + rx);
    __builtin_amdgcn_s_barrier();
    __builtin_amdgcn_s_setprio(1);
    #pragma unroll
    for (int mi=0;mi<4;++mi)
      #pragma unroll
      for (int ni=2;ni<4;++ni)
        acc[mi][ni] = __builtin_amdgcn_mfma_f32_16x16x32_fp8_fp8(af[mi], bfr[ni], acc[mi][ni], 0, 0, 0);
    __builtin_amdgcn_s_setprio(0);
    __builtin_amdgcn_s_barrier();
    __builtin_amdgcn_sched_barrier(0);
    if (pf) { async4(BT+srcBoff[0]+kk, bufn + 8192 + dstb); async4(BT+srcBoff[1]+kk, bufn + 10240 + dstb); }
    #pragma unroll
    for (int i=4;i<8;++i) af[i] = *(const long*)(lA + (wm*128 + i*16)*32 + rx);
    __builtin_amdgcn_s_barrier();
    __builtin_amdgcn_s_setprio(1);
    #pragma unroll
    for (int mi=4;mi<8;++mi)
      #pragma unroll
      for (int ni=0;ni<2;++ni)
        acc[mi][ni] = __builtin_amdgcn_mfma_f32_16x16x32_fp8_fp8(af[mi], bfr[ni], acc[mi][ni], 0, 0, 0);
    __builtin_amdgcn_s_setprio(0);
    __builtin_amdgcn_s_barrier();
    __builtin_amdgcn_sched_barrier(0);
    if (pf) { async4(BT+srcBoff[2]+kk, bufn + 12288 + dstb); async4(BT+srcBoff[3]+kk, bufn + 14336 + dstb); }
    __builtin_amdgcn_s_barrier();
    __builtin_amdgcn_s_setprio(1);
    #pragma unroll
    for (int mi=4;mi<8;++mi)
      #pragma unroll
      for (int ni=2;ni<4;++ni)
        acc[mi][ni] = __builtin_amdgcn_mfma_f32_16x16x32_fp8_fp8(af[mi], bfr[ni], acc[mi][ni], 0, 0, 0);
    __builtin_amdgcn_s_setprio(0);
    __builtin_amdgcn_sched_barrier(0);
    cur = (cur==2) ? 0 : cur+1;
    nxt = (nxt==2) ? 0 : nxt+1;
  }
  const int rowb = (lane>>4)*4, col = lane&15;
  #pragma unroll
  for (int mi=0;mi<8;++mi) {
    #pragma unroll
    for (int ni=0;ni<4;++ni) {
      const int gn = bn + wn*64 + ni*16 + col;
      const float bv = bias0[gn];
      const int h = gn >> 6, hd = gn & 63;
      #pragma unroll
      for (int r=0;r<4;++r) {
        const int gm = bm + wm*128 + mi*16 + rowb + r;
        const int b = gm >> 12, pix = gm & 4095;
        outp[(((size_t)(b*HH_+h)*LIN_ + pix)<<6) + hd] = to_fp8(acc[mi][ni][r] + bv);
      }
    }
  }
}

// 256x256 tile bf16 GEMM (r8/r11-verified), MODE 2: residual out (f32).
template<int MODE>
__global__ __launch_bounds__(512, 2) void k_gemm256(const bf16* __restrict__ A, const bf16* __restrict__ BT,
                                                    const float* __restrict__ bias0, void* __restrict__ outp,
                                                    const float* __restrict__ query, const float* __restrict__ gamma) {
  __shared__ char lds[98304];
  const int K = D_;
  const int tid = threadIdx.x, wid = tid>>6, lane = tid&63;
  const int nwg = gridDim.x*gridDim.y;
  const int d = blockIdx.y*gridDim.x + blockIdx.x;
  const int logical = (d & 7)*(nwg>>3) + (d>>3);
  const int bm = (logical/3)*256, bn = (logical%3)*256;
  const int wm = wid>>2, wn = wid&3;
  const int srow = tid>>2;
  const int sslot = ((tid&3) ^ ((tid>>3)&3))*8;
  const bf16* gA0 = A  + (size_t)(bm + srow)*K + sslot;
  const bf16* gA1 = A  + (size_t)(bm + 128 + srow)*K + sslot;
  const bf16* gB0 = BT + (size_t)(bn + srow)*K + sslot;
  const bf16* gB1 = BT + (size_t)(bn + 128 + srow)*K + sslot;
  const int dstbase = (tid>>6)<<10;
  const int rb = (lane&15)*64 + ((((lane>>4) ^ ((lane>>1)&3)))<<4);
  floatx4 acc[8][4] = {};
  auto stageAll = [&](int k0, char* buf) {
    async16(gA0+k0, buf + dstbase);
    async16(gA1+k0, buf + 8192 + dstbase);
    async16(gB0+k0, buf + 16384 + dstbase);
    async16(gB1+k0, buf + 24576 + dstbase);
  };
  stageAll(0,  lds);
  stageAll(32, lds + 32768);
  const int NT = K >> 5;
  int cur = 0, nxt = 2;
  for (int k = 0; k < NT; ++k) {
    if (k < NT-1) asm volatile("s_waitcnt vmcnt(4)" ::: "memory");
    else          asm volatile("s_waitcnt vmcnt(0)" ::: "memory");
    __builtin_amdgcn_s_barrier();
    __builtin_amdgcn_sched_barrier(0);
    const int kk = (k+2)*32;
    const bool pf = (k+2 < NT);
    const char* lA = lds + cur*32768;
    const char* lB = lA + 16384;
    char* bufn = lds + nxt*32768;
    short8 af[8], bfr[4];
    if (pf) async16(gA0+kk, bufn + dstbase);
    #pragma unroll
    for (int i=0;i<4;++i) af[i] = *(const short8*)(lA + (wm*128 + i*16)*64 + rb);
    #pragma unroll
    for (int i=0;i<2;++i) bfr[i] = *(const short8*)(lB + (wn*64 + i*16)*64 + rb);
    __builtin_amdgcn_s_barrier();
    __builtin_amdgcn_s_setprio(1);
    #pragma unroll
    for (int mi=0;mi<4;++mi)
      #pragma unroll
      for (int ni=0;ni<2;++ni)
        acc[mi][ni] = __builtin_amdgcn_mfma_f32_16x16x32_bf16(af[mi], bfr[ni], acc[mi][ni], 0, 0, 0);
    __builtin_amdgcn_s_setprio(0);
    __builtin_amdgcn_s_barrier();
    __builtin_amdgcn_sched_barrier(0);
    if (pf) async16(gA1+kk, bufn + 8192 + dstbase);
    #pragma unroll
    for (int i=2;i<4;++i) bfr[i] = *(const short8*)(lB + (wn*64 + i*16)*64 + rb);
    __builtin_amdgcn_s_barrier();
    __builtin_amdgcn_s_setprio(1);
    #pragma unroll
    for (int mi=0;mi<4;++mi)
      #pragma unroll
      for (int ni=2;ni<4;++ni)
        acc[mi][ni] = __builtin_amdgcn_mfma_f32_16x16x32_bf16(af[mi], bfr[ni], acc[mi][ni], 0, 0, 0);
    __builtin_amdgcn_s_setprio(0);
    __builtin_amdgcn_s_barrier();
    __builtin_amdgcn_sched_barrier(0);
    if (pf) async16(gB0+kk, bufn + 16384 + dstbase);
    #pragma unroll
    for (int i=4;i<8;++i) af[i] = *(const short8*)(lA + (wm*128 + i*16)*64 + rb);
    __builtin_amdgcn_s_barrier();
    __builtin_amdgcn_s_setprio(1);
    #pragma unroll
    for (int mi=4;mi<8;++mi)
      #pragma unroll
      for (int ni=0;ni<2;++ni)
        acc[mi][ni] = __builtin_amdgcn_mfma_f32_16x16x32_bf16(af[mi], bfr[ni], acc[mi][ni], 0, 0, 0);
    __builtin_amdgcn_s_setprio(0);
    __builtin_amdgcn_s_barrier();
    __builtin_amdgcn_sched_barrier(0);
    if (pf) async16(gB1+kk, bufn + 24576 + dstbase);
    __builtin_amdgcn_s_barrier();
    __builtin_amdgcn_s_setprio(1);
    #pragma unroll
    for (int mi=4;mi<8;++mi)
      #pragma unroll
      for (int ni=2;ni<4;++ni)
        acc[mi][ni] = __builtin_amdgcn_mfma_f32_16x16x32_bf16(af[mi], bfr[ni], acc[mi][ni], 0, 0, 0);
    __builtin_amdgcn_s_setprio(0);
    __builtin_amdgcn_sched_barrier(0);
    cur = (cur==2) ? 0 : cur+1;
    nxt = (nxt==2) ? 0 : nxt+1;
  }
  const int rowb = (lane>>4)*4, col = lane&15;
  #pragma unroll
  for (int mi=0;mi<8;++mi) {
    #pragma unroll
    for (int ni=0;ni<4;++ni) {
      const int gn = bn + wn*64 + ni*16 + col;
      const float bv = bias0[gn];
      #pragma unroll
      for (int r=0;r<4;++r) {
        const int gm = bm + wm*128 + mi*16 + rowb + r;
        const int bq = gm >> 10, lq = gm & 1023;
        size_t idx = ((size_t)bq*QR_ + TASK_ + lq)*D_ + gn;
        ((float*)outp)[idx] = query[idx] + gamma[gn]*(acc[mi][ni][r] + bv);
      }
    }
  }
}

// gather+combine (r8-verified structure; fp8 value decode via HW cvt).
__global__ __launch_bounds__(256) void k_sample(const char* __restrict__ prepc,
                                                const unsigned char* __restrict__ value,
                                                bf16* __restrict__ sampout) {
  int g  = blockIdx.x*8 + (threadIdx.x>>5);   // (b*1024+q)*12 + h
  int l  = threadIdx.x & 31;
  int c8 = l >> 2, p = l & 3;
  int h = g % HH_, m = g / HH_;
  int b = m >> 10;
  const char* gb = prepc + (size_t)g*64;
  short4v wq = *(const short4v*)(gb + p*8);
  short4v pq = *(const short4v*)(gb + 32 + p*8);
  const unsigned char* vb = value + (((size_t)(b*HH_+h))<<18) + (c8<<3);
  float a[8] = {};
  #pragma unroll
  for (int c=0;c<4;++c) {
    float w = __uint_as_float(((unsigned)(unsigned short)wq[c])<<16);
    int pix = (int)(unsigned short)pq[c];
    uint2 d = *(const uint2*)(vb + ((size_t)pix<<6));
    floatx2 f0 = __builtin_amdgcn_cvt_pk_f32_fp8(d.x, false);
    floatx2 f1 = __builtin_amdgcn_cvt_pk_f32_fp8(d.x, true);
    floatx2 f2 = __builtin_amdgcn_cvt_pk_f32_fp8(d.y, false);
    floatx2 f3 = __builtin_amdgcn_cvt_pk_f32_fp8(d.y, true);
    a[0] += w*f0.x; a[1] += w*f0.y;
    a[2] += w*f1.x; a[3] += w*f1.y;
    a[4] += w*f2.x; a[5] += w*f2.y;
    a[6] += w*f3.x; a[7] += w*f3.y;
  }
  #pragma unroll
  for (int j=0;j<8;++j) { a[j] += __shfl_xor(a[j],1); a[j] += __shfl_xor(a[j],2); }
  if (p == 0) {
    short8 o;
    #pragma unroll
    for (int j=0;j<8;++j)
      o[j] = (short)__bfloat16_as_ushort(__float2bfloat16(a[j]));
    *(short8*)(sampout + (size_t)m*D_ + h*64 + c8*8) = o;
  }
}

extern "C" void kernel_launch(void* const* d_in, const int* in_sizes, int n_in,
                              void* d_out, int out_size, void* d_ws, size_t ws_size,
                              hipStream_t stream) {
  (void)in_sizes; (void)n_in; (void)out_size; (void)ws_size;
  const float* query = (const float*)d_in[0];
  const float* refp  = (const float*)d_in[1];
  const float* feat  = (const float*)d_in[2];
  const float* qn_w  = (const float*)d_in[5];
  const float* qn_b  = (const float*)d_in[6];
  const float* fn_w  = (const float*)d_in[7];
  const float* fn_b  = (const float*)d_in[8];
  const float* gamma = (const float*)d_in[9];
  const float* W_off = (const float*)d_in[10];
  const float* b_off = (const float*)d_in[11];
  const float* W_attw= (const float*)d_in[12];
  const float* b_attw= (const float*)d_in[13];
  const float* W_val = (const float*)d_in[14];
  const float* b_val = (const float*)d_in[15];
  const float* W_out = (const float*)d_in[16];
  const float* b_out = (const float*)d_in[17];
  char*  ws  = (char*)d_ws;
  float* out = (float*)d_out;

  unsigned char* wsVal = (unsigned char*)(ws + OFF_VAL);
  unsigned char* wsFn8 = (unsigned char*)(ws + OFF_FN);
  bf16* wsQn   = (bf16*)(ws + OFF_QN);
  char* wsPrep = ws + OFF_PREP;
  unsigned char* wsWvT8 = (unsigned char*)(ws + OFF_WVT);
  bf16* wsWoT  = (bf16*)(ws + OFF_WOT);
  bf16* wsWcT  = (bf16*)(ws + OFF_WCT);
  bf16* wsSamp = (bf16*)(ws + OFF_FN);   // fn dead after value GEMM

  k_wln<<<1056 + 2048, 256, 0, stream>>>(W_val, W_out, W_off, W_attw, wsWvT8, wsWoT, wsWcT,
                                         query, feat, qn_w, qn_b, fn_w, fn_b, wsQn, wsFn8);
  k_offprep<<<MQ_/64, 256, 0, stream>>>(wsQn, wsWcT, b_off, b_attw, refp, wsPrep, query, out);
  k_gemm_fp8<<<dim3(MF_/256, 3), 512, 0, stream>>>(wsFn8, wsWvT8, b_val, wsVal);
  k_sample<<<(MQ_*HH_)/8, 256, 0, stream>>>(wsPrep, wsVal, wsSamp);
  k_gemm256<2><<<dim3(MQ_/256, 3), 512, 0, stream>>>(wsSamp, wsWoT, b_out, out, query, gamma);
}

// Round 18
// 242.021 us; speedup vs baseline: 1.0456x; 1.0456x over previous
//
#include <hip/hip_runtime.h>
#include <hip/hip_bf16.h>

using bf16 = __hip_bfloat16;
typedef __attribute__((ext_vector_type(8))) short short8;
typedef __attribute__((ext_vector_type(4))) short short4v;
typedef __attribute__((ext_vector_type(4))) float floatx4;
typedef __attribute__((ext_vector_type(2))) float floatx2;

#define B_    16
#define TASK_ 80
#define LQ_   1024
#define D_    768
#define HH_   12
#define HD_   64
#define LIN_  4096
#define MQ_   (B_*LQ_)     // 16384 query rows
#define MF_   (B_*LIN_)    // 65536 feat rows
#define QR_   (TASK_+LQ_)  // 1104

// ---- workspace layout (bytes) ----
static constexpr size_t OFF_VAL  = 0;                               // fp8 value (B,HH,LIN,HD)
static constexpr size_t OFF_FN   = OFF_VAL + (size_t)MF_*D_*2;      // fp8 fn (MF,768); reused as bf16 sampout
static constexpr size_t OFF_QN   = OFF_FN  + (size_t)MF_*D_*2;      // bf16 qn (MQ,768)
static constexpr size_t OFF_PREP = OFF_QN  + (size_t)MQ_*D_*2;      // compressed prep: 196608 groups x 64B
static constexpr size_t OFF_WVT  = OFF_PREP + (size_t)MQ_*HH_*64;   // fp8 W_val^T (768,768)
static constexpr size_t OFF_WOT  = OFF_WVT + (size_t)D_*D_*2;       // bf16 W_out^T (768,768)
static constexpr size_t OFF_WCT  = OFF_WOT + (size_t)D_*D_*2;       // bf16 Wcat^T (256,768)

__device__ __forceinline__ void async16(const void* g, void* l) {
  __builtin_amdgcn_global_load_lds((const __attribute__((address_space(1))) void*)g,
                                   (__attribute__((address_space(3))) void*)l, 16, 0, 0);
}
__device__ __forceinline__ void async4(const void* g, void* l) {
  __builtin_amdgcn_global_load_lds((const __attribute__((address_space(1))) void*)g,
                                   (__attribute__((address_space(3))) void*)l, 4, 0, 0);
}
__device__ __forceinline__ unsigned char to_fp8(float v) {
  return (unsigned char)(__builtin_amdgcn_cvt_pk_fp8_f32(v, v, 0, false) & 0xff);
}

// merged weight-prep + LayerNorm. W_val^T and fn are emitted as fp8 e4m3.
// (r16-verified: one row per wave, loads hoisted, normal stores.)
__global__ __launch_bounds__(256) void k_wln(const float* __restrict__ Wv, const float* __restrict__ Wo,
                                             const float* __restrict__ Woff, const float* __restrict__ Wat,
                                             unsigned char* __restrict__ WvT8, bf16* __restrict__ WoT,
                                             bf16* __restrict__ WcT,
                                             const float* __restrict__ query, const float* __restrict__ feat,
                                             const float* __restrict__ qw, const float* __restrict__ qb,
                                             const float* __restrict__ fw, const float* __restrict__ fb,
                                             bf16* __restrict__ qn, unsigned char* __restrict__ fn8) {
  __shared__ float t[64][65];
  int bid = blockIdx.x;
  if (bid < 288) {
    const float* W = (bid < 144) ? Wv : Wo;
    int lb = (bid < 144) ? bid : bid - 144;
    int bx = lb % 12, by = lb / 12;
    int n0 = bx*64, k0 = by*64;
    int col = threadIdx.x & 63, rg = threadIdx.x >> 6;
    #pragma unroll
    for (int i=0;i<16;++i) { int row = i*4+rg; t[row][col] = W[(size_t)(k0+row)*D_ + n0+col]; }
    __syncthreads();
    if (bid < 144) {
      #pragma unroll
      for (int i=0;i<16;++i) { int row = i*4+rg; WvT8[(size_t)(n0+row)*D_ + k0+col] = to_fp8(t[col][row]); }
    } else {
      #pragma unroll
      for (int i=0;i<16;++i) { int row = i*4+rg; WoT[(size_t)(n0+row)*D_ + k0+col] = __float2bfloat16(t[col][row]); }
    }
    return;
  }
  if (bid < 1056) {
    int idx = (bid-288)*256 + threadIdx.x;     // over 256*768, exact
    int j = idx / D_, k = idx - j*D_;
    float v = 0.f;
    if (j < 96)       v = Woff[(size_t)k*96 + j];
    else if (j < 144) v = Wat[(size_t)k*48 + (j-96)];
    WcT[idx] = __float2bfloat16(v);
    return;
  }
  int r = (bid-1056)*4 + (threadIdx.x>>6);
  int lane = threadIdx.x & 63;
  const bool isQ = (r < MQ_);
  const float* src; const float* w; const float* bia;
  bf16* dstq = nullptr; unsigned char* dstf = nullptr;
  if (isQ) {
    int bat = r >> 10, rr = r & 1023;
    src = query + ((size_t)bat*QR_ + TASK_ + rr)*D_;
    w = qw; bia = qb; dstq = qn + (size_t)r*D_;
  } else {
    int fr = r - MQ_;
    src = feat + (size_t)fr*D_;
    w = fw; bia = fb; dstf = fn8 + (size_t)fr*D_;
  }
  float4 v[3], ww[3], bb[3];
  #pragma unroll
  for (int j=0;j<3;++j) v[j]  = ((const float4*)src)[lane + 64*j];
  #pragma unroll
  for (int j=0;j<3;++j) ww[j] = ((const float4*)w)[lane + 64*j];
  #pragma unroll
  for (int j=0;j<3;++j) bb[j] = ((const float4*)bia)[lane + 64*j];
  float s = 0.f, s2 = 0.f;
  #pragma unroll
  for (int j=0;j<3;++j) {
    s  += v[j].x + v[j].y + v[j].z + v[j].w;
    s2 += v[j].x*v[j].x + v[j].y*v[j].y + v[j].z*v[j].z + v[j].w*v[j].w;
  }
  #pragma unroll
  for (int o=32;o>0;o>>=1){ s += __shfl_xor(s,o); s2 += __shfl_xor(s2,o); }
  float mu  = s*(1.f/D_);
  float var = s2*(1.f/D_) - mu*mu;
  float rstd = rsqrtf(var + 1e-6f);
  #pragma unroll
  for (int j=0;j<3;++j) {
    float r0 = (v[j].x-mu)*rstd*ww[j].x + bb[j].x;
    float r1 = (v[j].y-mu)*rstd*ww[j].y + bb[j].y;
    float r2 = (v[j].z-mu)*rstd*ww[j].z + bb[j].z;
    float r3 = (v[j].w-mu)*rstd*ww[j].w + bb[j].w;
    if (isQ) {
      short4v o4;
      o4[0] = (short)__bfloat16_as_ushort(__float2bfloat16(r0));
      o4[1] = (short)__bfloat16_as_ushort(__float2bfloat16(r1));
      o4[2] = (short)__bfloat16_as_ushort(__float2bfloat16(r2));
      o4[3] = (short)__bfloat16_as_ushort(__float2bfloat16(r3));
      *(short4v*)(dstq + 4*(lane + 64*j)) = o4;
    } else {
      unsigned lo = (unsigned)__builtin_amdgcn_cvt_pk_fp8_f32(r0, r1, 0, false);
      unsigned pk = (unsigned)__builtin_amdgcn_cvt_pk_fp8_f32(r2, r3, (int)lo, true);
      *(unsigned*)(dstf + 4*(lane + 64*j)) = pk;
    }
  }
}

// fused off/attw GEMM + prep + copytt (r11-verified).
__global__ __launch_bounds__(256) void k_offprep(const bf16* __restrict__ A, const bf16* __restrict__ BT,
                                                 const float* __restrict__ b_off, const float* __restrict__ b_attw,
                                                 const float* __restrict__ refp, char* __restrict__ prepc,
                                                 const float* __restrict__ query, float* __restrict__ out) {
  __shared__ char lds[49152];
  const int tid = threadIdx.x, wid = tid>>6, lane = tid&63;
  const int bm = blockIdx.x*64;
  const int K = D_;
  const int srow = tid>>2;
  const int skb = ((tid&3) ^ ((tid>>3)&3))*8;
  const bf16* gA  = A  + (size_t)(bm + srow)*K + skb;
  const bf16* gB  = BT + (size_t)srow*K + skb;
  const int dstbase = wid<<10;
  const int rb = (lane&15)*64 + ((((lane>>4) ^ ((lane>>1)&3)))<<4);
  floatx4 acc[4][3] = {};
  auto stage = [&](int k0, char* buf) {
    async16(gA + k0,                 buf + dstbase);
    async16(gB + k0,                 buf + 4096  + dstbase);
    async16(gB + (size_t)64*K + k0,  buf + 8192  + dstbase);
    async16(gB + (size_t)128*K + k0, buf + 12288 + dstbase);
  };
  stage(0,  lds);
  stage(32, lds + 16384);
  const int NT = K >> 5;
  int cur = 0, nxt = 2;
  for (int k = 0; k < NT; ++k) {
    if (k < NT-1) asm volatile("s_waitcnt vmcnt(4)" ::: "memory");
    else          asm volatile("s_waitcnt vmcnt(0)" ::: "memory");
    __builtin_amdgcn_s_barrier();
    __builtin_amdgcn_sched_barrier(0);
    if (k + 2 < NT) stage((k+2)*32, lds + nxt*16384);
    const char* ldsA = lds + cur*16384; const char* ldsB = ldsA + 4096;
    short8 af[4], bf[3];
    #pragma unroll
    for (int i=0;i<4;++i) af[i] = *(const short8*)(ldsA + (i*16)*64 + rb);
    #pragma unroll
    for (int j=0;j<3;++j) bf[j] = *(const short8*)(ldsB + (wid*48 + j*16)*64 + rb);
    #pragma unroll
    for (int mi=0;mi<4;++mi)
      #pragma unroll
      for (int ni=0;ni<3;++ni)
        acc[mi][ni] = __builtin_amdgcn_mfma_f32_16x16x32_bf16(af[mi], bf[ni], acc[mi][ni], 0, 0, 0);
    cur = (cur==2) ? 0 : cur+1;
    nxt = (nxt==2) ? 0 : nxt+1;
  }
  __syncthreads();
  float* oa = (float*)lds;         // [64][148]
  const int rowb = (lane>>4)*4, col = lane&15;
  #pragma unroll
  for (int mi=0;mi<4;++mi) {
    #pragma unroll
    for (int ni=0;ni<3;++ni) {
      const int gn = wid*48 + ni*16 + col;
      if (gn < 144) {
        const float bv = (gn < 96) ? b_off[gn] : b_attw[gn-96];
        #pragma unroll
        for (int r=0;r<4;++r) {
          const int rl = mi*16 + rowb + r;
          oa[rl*148 + gn] = acc[mi][ni][r] + bv;
        }
      }
    }
  }
  __syncthreads();
  #pragma unroll
  for (int i=0;i<12;++i) {
    int item = tid + i*256;
    int rl = item / 48;
    int hp = item - rl*48;
    int h = hp >> 2, p = hp & 3;
    int m = bm + rl;
    const float* row = oa + rl*148;
    float l0 = row[96+h*4+0], l1 = row[96+h*4+1], l2 = row[96+h*4+2], l3 = row[96+h*4+3];
    float mx = fmaxf(fmaxf(l0,l1), fmaxf(l2,l3));
    float e0 = expf(l0-mx), e1 = expf(l1-mx), e2 = expf(l2-mx), e3 = expf(l3-mx);
    float inv = 1.f/(e0+e1+e2+e3);
    float ep = (p==0)?e0:(p==1)?e1:(p==2)?e2:e3;
    float awp = ep*inv;
    float x = refp[(size_t)m*2+0]*64.f - 0.5f + row[h*8+p*2+0];
    float y = refp[(size_t)m*2+1]*64.f - 0.5f + row[h*8+p*2+1];
    float x0f = floorf(x), y0f = floorf(y);
    int ix = (int)x0f, iy = (int)y0f;
    float fx = x-x0f, fy = y-y0f;
    float wx[2] = {1.f-fx, fx}, wy[2] = {1.f-fy, fy};
    short4v wq, pq;
    #pragma unroll
    for (int c=0;c<4;++c) {
      int dx = c&1, dy = c>>1;
      int xc = ix+dx, yc = iy+dy;
      bool valid = ((unsigned)xc < 64u) && ((unsigned)yc < 64u);
      float w = valid ? awp*wx[dx]*wy[dy] : 0.f;
      int xi = min(max(xc,0),63), yi = min(max(yc,0),63);
      wq[c] = (short)__bfloat16_as_ushort(__float2bfloat16(w));
      pq[c] = (short)(yi*64+xi);
    }
    char* gb = prepc + ((size_t)(m*HH_ + h))*64;
    *(short4v*)(gb + p*8)      = wq;
    *(short4v*)(gb + 32 + p*8) = pq;
  }
  #pragma unroll
  for (int i=0;i<4;++i) {
    int ci = blockIdx.x*256 + tid + i*65536;
    if (ci < B_*TASK_*D_/4) {
      const int perb = TASK_*D_/4;
      int b = ci / perb, r = ci - b*perb;
      const float4* s = (const float4*)(query + (size_t)b*QR_*D_) + r;
      float4* dd = (float4*)(out + (size_t)b*QR_*D_) + r;
      *dd = *s;
    }
  }
}

// fp8 x fp8 value GEMM (r16-verified): 256x256, 4-phase double-barrier
// lockstep, ring-3, counted vmcnt(8), width-4 swizzled staging.
__global__ __launch_bounds__(512, 2) void k_gemm_fp8(const unsigned char* __restrict__ A,
                                                     const unsigned char* __restrict__ BT,
                                                     const float* __restrict__ bias0,
                                                     unsigned char* __restrict__ outp) {
  __shared__ char lds[49152];    // 3 x (A 8KB + B 8KB)
  const int tid = threadIdx.x, wid = tid>>6, lane = tid&63;
  const int nwg = gridDim.x*gridDim.y;            // 768; %8==0
  const int d = blockIdx.y*gridDim.x + blockIdx.x;
  const int logical = (d & 7)*(nwg>>3) + (d>>3);  // XCD-chunked
  const int bm = (logical/3)*256, bn = (logical%3)*256;
  const int wm = wid>>2, wn = wid&3;              // wave tile 128x64
  int srcAoff[4], srcBoff[4];
  #pragma unroll
  for (int i=0;i<4;++i) {
    int g = wid*64 + lane + i*512;
    int row = g >> 3, sp = (g>>1)&3, half = g&1;
    int s = sp ^ ((row>>2)&3);
    srcAoff[i] = (bm + row)*D_ + s*8 + half*4;
    srcBoff[i] = (bn + row)*D_ + s*8 + half*4;
  }
  const int dstb = wid*256;
  const int rx = (lane&15)*32 + ((((lane>>4) ^ ((lane>>2)&3)))<<3);
  floatx4 acc[8][4] = {};
  auto stageAll = [&](int k0, char* buf) {
    #pragma unroll
    for (int i=0;i<4;++i) async4(A + srcAoff[i] + k0, buf + i*2048 + dstb);
    #pragma unroll
    for (int i=0;i<4;++i) async4(BT + srcBoff[i] + k0, buf + 8192 + i*2048 + dstb);
  };
  stageAll(0,  lds);
  stageAll(32, lds + 16384);
  const int NT = D_ >> 5;     // 24
  int cur = 0, nxt = 2;
  for (int k = 0; k < NT; ++k) {
    if (k < NT-1) asm volatile("s_waitcnt vmcnt(8)" ::: "memory");
    else          asm volatile("s_waitcnt vmcnt(0)" ::: "memory");
    __builtin_amdgcn_s_barrier();
    __builtin_amdgcn_sched_barrier(0);
    const int kk = (k+2)*32;
    const bool pf = (k+2 < NT);
    const char* lA = lds + cur*16384;
    const char* lB = lA + 8192;
    char* bufn = lds + nxt*16384;
    long af[8], bfr[4];
    if (pf) { async4(A+srcAoff[0]+kk, bufn + dstb); async4(A+srcAoff[1]+kk, bufn + 2048 + dstb); }
    #pragma unroll
    for (int i=0;i<4;++i) af[i] = *(const long*)(lA + (wm*128 + i*16)*32 + rx);
    #pragma unroll
    for (int i=0;i<2;++i) bfr[i] = *(const long*)(lB + (wn*64 + i*16)*32 + rx);
    __builtin_amdgcn_s_barrier();
    __builtin_amdgcn_s_setprio(1);
    #pragma unroll
    for (int mi=0;mi<4;++mi)
      #pragma unroll
      for (int ni=0;ni<2;++ni)
        acc[mi][ni] = __builtin_amdgcn_mfma_f32_16x16x32_fp8_fp8(af[mi], bfr[ni], acc[mi][ni], 0, 0, 0);
    __builtin_amdgcn_s_setprio(0);
    __builtin_amdgcn_s_barrier();
    __builtin_amdgcn_sched_barrier(0);
    if (pf) { async4(A+srcAoff[2]+kk, bufn + 4096 + dstb); async4(A+srcAoff[3]+kk, bufn + 6144 + dstb); }
    #pragma unroll
    for (int i=2;i<4;++i) bfr[i] = *(const long*)(lB + (wn*64 + i*16)*32 + rx);
    __builtin_amdgcn_s_barrier();
    __builtin_amdgcn_s_setprio(1);
    #pragma unroll
    for (int mi=0;mi<4;++mi)
      #pragma unroll
      for (int ni=2;ni<4;++ni)
        acc[mi][ni] = __builtin_amdgcn_mfma_f32_16x16x32_fp8_fp8(af[mi], bfr[ni], acc[mi][ni], 0, 0, 0);
    __builtin_amdgcn_s_setprio(0);
    __builtin_amdgcn_s_barrier();
    __builtin_amdgcn_sched_barrier(0);
    if (pf) { async4(BT+srcBoff[0]+kk, bufn + 8192 + dstb); async4(BT+srcBoff[1]+kk, bufn + 10240 + dstb); }
    #pragma unroll
    for (int i=4;i<8;++i) af[i] = *(const long*)(lA + (wm*128 + i*16)*32 + rx);
    __builtin_amdgcn_s_barrier();
    __builtin_amdgcn_s_setprio(1);
    #pragma unroll
    for (int mi=4;mi<8;++mi)
      #pragma unroll
      for (int ni=0;ni<2;++ni)
        acc[mi][ni] = __builtin_amdgcn_mfma_f32_16x16x32_fp8_fp8(af[mi], bfr[ni], acc[mi][ni], 0, 0, 0);
    __builtin_amdgcn_s_setprio(0);
    __builtin_amdgcn_s_barrier();
    __builtin_amdgcn_sched_barrier(0);
    if (pf) { async4(BT+srcBoff[2]+kk, bufn + 12288 + dstb); async4(BT+srcBoff[3]+kk, bufn + 14336 + dstb); }
    __builtin_amdgcn_s_barrier();
    __builtin_amdgcn_s_setprio(1);
    #pragma unroll
    for (int mi=4;mi<8;++mi)
      #pragma unroll
      for (int ni=2;ni<4;++ni)
        acc[mi][ni] = __builtin_amdgcn_mfma_f32_16x16x32_fp8_fp8(af[mi], bfr[ni], acc[mi][ni], 0, 0, 0);
    __builtin_amdgcn_s_setprio(0);
    __builtin_amdgcn_sched_barrier(0);
    cur = (cur==2) ? 0 : cur+1;
    nxt = (nxt==2) ? 0 : nxt+1;
  }
  const int rowb = (lane>>4)*4, col = lane&15;
  #pragma unroll
  for (int mi=0;mi<8;++mi) {
    #pragma unroll
    for (int ni=0;ni<4;++ni) {
      const int gn = bn + wn*64 + ni*16 + col;
      const float bv = bias0[gn];
      const int h = gn >> 6, hd = gn & 63;
      #pragma unroll
      for (int r=0;r<4;++r) {
        const int gm = bm + wm*128 + mi*16 + rowb + r;
        const int b = gm >> 12, pix = gm & 4095;
        outp[(((size_t)(b*HH_+h)*LIN_ + pix)<<6) + hd] = to_fp8(acc[mi][ni][r] + bv);
      }
    }
  }
}

// 256x256 tile bf16 GEMM (r8/r11-verified), MODE 2: residual out (f32).
template<int MODE>
__global__ __launch_bounds__(512, 2) void k_gemm256(const bf16* __restrict__ A, const bf16* __restrict__ BT,
                                                    const float* __restrict__ bias0, void* __restrict__ outp,
                                                    const float* __restrict__ query, const float* __restrict__ gamma) {
  __shared__ char lds[98304];
  const int K = D_;
  const int tid = threadIdx.x, wid = tid>>6, lane = tid&63;
  const int nwg = gridDim.x*gridDim.y;
  const int d = blockIdx.y*gridDim.x + blockIdx.x;
  const int logical = (d & 7)*(nwg>>3) + (d>>3);
  const int bm = (logical/3)*256, bn = (logical%3)*256;
  const int wm = wid>>2, wn = wid&3;
  const int srow = tid>>2;
  const int sslot = ((tid&3) ^ ((tid>>3)&3))*8;
  const bf16* gA0 = A  + (size_t)(bm + srow)*K + sslot;
  const bf16* gA1 = A  + (size_t)(bm + 128 + srow)*K + sslot;
  const bf16* gB0 = BT + (size_t)(bn + srow)*K + sslot;
  const bf16* gB1 = BT + (size_t)(bn + 128 + srow)*K + sslot;
  const int dstbase = (tid>>6)<<10;
  const int rb = (lane&15)*64 + ((((lane>>4) ^ ((lane>>1)&3)))<<4);
  floatx4 acc[8][4] = {};
  auto stageAll = [&](int k0, char* buf) {
    async16(gA0+k0, buf + dstbase);
    async16(gA1+k0, buf + 8192 + dstbase);
    async16(gB0+k0, buf + 16384 + dstbase);
    async16(gB1+k0, buf + 24576 + dstbase);
  };
  stageAll(0,  lds);
  stageAll(32, lds + 32768);
  const int NT = K >> 5;
  int cur = 0, nxt = 2;
  for (int k = 0; k < NT; ++k) {
    if (k < NT-1) asm volatile("s_waitcnt vmcnt(4)" ::: "memory");
    else          asm volatile("s_waitcnt vmcnt(0)" ::: "memory");
    __builtin_amdgcn_s_barrier();
    __builtin_amdgcn_sched_barrier(0);
    const int kk = (k+2)*32;
    const bool pf = (k+2 < NT);
    const char* lA = lds + cur*32768;
    const char* lB = lA + 16384;
    char* bufn = lds + nxt*32768;
    short8 af[8], bfr[4];
    if (pf) async16(gA0+kk, bufn + dstbase);
    #pragma unroll
    for (int i=0;i<4;++i) af[i] = *(const short8*)(lA + (wm*128 + i*16)*64 + rb);
    #pragma unroll
    for (int i=0;i<2;++i) bfr[i] = *(const short8*)(lB + (wn*64 + i*16)*64 + rb);
    __builtin_amdgcn_s_barrier();
    __builtin_amdgcn_s_setprio(1);
    #pragma unroll
    for (int mi=0;mi<4;++mi)
      #pragma unroll
      for (int ni=0;ni<2;++ni)
        acc[mi][ni] = __builtin_amdgcn_mfma_f32_16x16x32_bf16(af[mi], bfr[ni], acc[mi][ni], 0, 0, 0);
    __builtin_amdgcn_s_setprio(0);
    __builtin_amdgcn_s_barrier();
    __builtin_amdgcn_sched_barrier(0);
    if (pf) async16(gA1+kk, bufn + 8192 + dstbase);
    #pragma unroll
    for (int i=2;i<4;++i) bfr[i] = *(const short8*)(lB + (wn*64 + i*16)*64 + rb);
    __builtin_amdgcn_s_barrier();
    __builtin_amdgcn_s_setprio(1);
    #pragma unroll
    for (int mi=0;mi<4;++mi)
      #pragma unroll
      for (int ni=2;ni<4;++ni)
        acc[mi][ni] = __builtin_amdgcn_mfma_f32_16x16x32_bf16(af[mi], bfr[ni], acc[mi][ni], 0, 0, 0);
    __builtin_amdgcn_s_setprio(0);
    __builtin_amdgcn_s_barrier();
    __builtin_amdgcn_sched_barrier(0);
    if (pf) async16(gB0+kk, bufn + 16384 + dstbase);
    #pragma unroll
    for (int i=4;i<8;++i) af[i] = *(const short8*)(lA + (wm*128 + i*16)*64 + rb);
    __builtin_amdgcn_s_barrier();
    __builtin_amdgcn_s_setprio(1);
    #pragma unroll
    for (int mi=4;mi<8;++mi)
      #pragma unroll
      for (int ni=0;ni<2;++ni)
        acc[mi][ni] = __builtin_amdgcn_mfma_f32_16x16x32_bf16(af[mi], bfr[ni], acc[mi][ni], 0, 0, 0);
    __builtin_amdgcn_s_setprio(0);
    __builtin_amdgcn_s_barrier();
    __builtin_amdgcn_sched_barrier(0);
    if (pf) async16(gB1+kk, bufn + 24576 + dstbase);
    __builtin_amdgcn_s_barrier();
    __builtin_amdgcn_s_setprio(1);
    #pragma unroll
    for (int mi=4;mi<8;++mi)
      #pragma unroll
      for (int ni=2;ni<4;++ni)
        acc[mi][ni] = __builtin_amdgcn_mfma_f32_16x16x32_bf16(af[mi], bfr[ni], acc[mi][ni], 0, 0, 0);
    __builtin_amdgcn_s_setprio(0);
    __builtin_amdgcn_sched_barrier(0);
    cur = (cur==2) ? 0 : cur+1;
    nxt = (nxt==2) ? 0 : nxt+1;
  }
  const int rowb = (lane>>4)*4, col = lane&15;
  #pragma unroll
  for (int mi=0;mi<8;++mi) {
    #pragma unroll
    for (int ni=0;ni<4;++ni) {
      const int gn = bn + wn*64 + ni*16 + col;
      const float bv = bias0[gn];
      #pragma unroll
      for (int r=0;r<4;++r) {
        const int gm = bm + wm*128 + mi*16 + rowb + r;
        const int bq = gm >> 10, lq = gm & 1023;
        size_t idx = ((size_t)bq*QR_ + TASK_ + lq)*D_ + gn;
        ((float*)outp)[idx] = query[idx] + gamma[gn]*(acc[mi][ni][r] + bv);
      }
    }
  }
}

// gather+combine (r8-verified structure; fp8 value decode via HW cvt).
__global__ __launch_bounds__(256) void k_sample(const char* __restrict__ prepc,
                                                const unsigned char* __restrict__ value,
                                                bf16* __restrict__ sampout) {
  int g  = blockIdx.x*8 + (threadIdx.x>>5);   // (b*1024+q)*12 + h
  int l  = threadIdx.x & 31;
  int c8 = l >> 2, p = l & 3;
  int h = g % HH_, m = g / HH_;
  int b = m >> 10;
  const char* gb = prepc + (size_t)g*64;
  short4v wq = *(const short4v*)(gb + p*8);
  short4v pq = *(const short4v*)(gb + 32 + p*8);
  const unsigned char* vb = value + (((size_t)(b*HH_+h))<<18) + (c8<<3);
  float a[8] = {};
  #pragma unroll
  for (int c=0;c<4;++c) {
    float w = __uint_as_float(((unsigned)(unsigned short)wq[c])<<16);
    int pix = (int)(unsigned short)pq[c];
    uint2 d = *(const uint2*)(vb + ((size_t)pix<<6));
    floatx2 f0 = __builtin_amdgcn_cvt_pk_f32_fp8(d.x, false);
    floatx2 f1 = __builtin_amdgcn_cvt_pk_f32_fp8(d.x, true);
    floatx2 f2 = __builtin_amdgcn_cvt_pk_f32_fp8(d.y, false);
    floatx2 f3 = __builtin_amdgcn_cvt_pk_f32_fp8(d.y, true);
    a[0] += w*f0.x; a[1] += w*f0.y;
    a[2] += w*f1.x; a[3] += w*f1.y;
    a[4] += w*f2.x; a[5] += w*f2.y;
    a[6] += w*f3.x; a[7] += w*f3.y;
  }
  #pragma unroll
  for (int j=0;j<8;++j) { a[j] += __shfl_xor(a[j],1); a[j] += __shfl_xor(a[j],2); }
  if (p == 0) {
    short8 o;
    #pragma unroll
    for (int j=0;j<8;++j)
      o[j] = (short)__bfloat16_as_ushort(__float2bfloat16(a[j]));
    *(short8*)(sampout + (size_t)m*D_ + h*64 + c8*8) = o;
  }
}

extern "C" void kernel_launch(void* const* d_in, const int* in_sizes, int n_in,
                              void* d_out, int out_size, void* d_ws, size_t ws_size,
                              hipStream_t stream) {
  (void)in_sizes; (void)n_in; (void)out_size; (void)ws_size;
  const float* query = (const float*)d_in[0];
  const float* refp  = (const float*)d_in[1];
  const float* feat  = (const float*)d_in[2];
  const float* qn_w  = (const float*)d_in[5];
  const float* qn_b  = (const float*)d_in[6];
  const float* fn_w  = (const float*)d_in[7];
  const float* fn_b  = (const float*)d_in[8];
  const float* gamma = (const float*)d_in[9];
  const float* W_off = (const float*)d_in[10];
  const float* b_off = (const float*)d_in[11];
  const float* W_attw= (const float*)d_in[12];
  const float* b_attw= (const float*)d_in[13];
  const float* W_val = (const float*)d_in[14];
  const float* b_val = (const float*)d_in[15];
  const float* W_out = (const float*)d_in[16];
  const float* b_out = (const float*)d_in[17];
  char*  ws  = (char*)d_ws;
  float* out = (float*)d_out;

  unsigned char* wsVal = (unsigned char*)(ws + OFF_VAL);
  unsigned char* wsFn8 = (unsigned char*)(ws + OFF_FN);
  bf16* wsQn   = (bf16*)(ws + OFF_QN);
  char* wsPrep = ws + OFF_PREP;
  unsigned char* wsWvT8 = (unsigned char*)(ws + OFF_WVT);
  bf16* wsWoT  = (bf16*)(ws + OFF_WOT);
  bf16* wsWcT  = (bf16*)(ws + OFF_WCT);
  bf16* wsSamp = (bf16*)(ws + OFF_FN);   // fn dead after value GEMM

  k_wln<<<1056 + (MQ_+MF_)/4, 256, 0, stream>>>(W_val, W_out, W_off, W_attw, wsWvT8, wsWoT, wsWcT,
                                                query, feat, qn_w, qn_b, fn_w, fn_b, wsQn, wsFn8);
  k_offprep<<<MQ_/64, 256, 0, stream>>>(wsQn, wsWcT, b_off, b_attw, refp, wsPrep, query, out);
  k_gemm_fp8<<<dim3(MF_/256, 3), 512, 0, stream>>>(wsFn8, wsWvT8, b_val, wsVal);
  k_sample<<<(MQ_*HH_)/8, 256, 0, stream>>>(wsPrep, wsVal, wsSamp);
  k_gemm256<2><<<dim3(MQ_/256, 3), 512, 0, stream>>>(wsSamp, wsWoT, b_out, out, query, gamma);
}